// Round 1
// baseline (23.553 us; speedup 1.0000x reference)
//
#include <hip/hip_runtime.h>

// y[i,o,n] = sum_{j,k} x[j,(o-1)%56, n+k-1]*W[i,j,0,k]
//          + sum_{j,k} x[j,(o-2)%56, n+k-1]*W[i,j,1,k]
// x: (1,64,56,56) f32, W: (64,64,2,3) f32 [i,j,l,k], y: (1,64,56,56) f32

#define O_DIM 56
#define N_DIM 56
#define J_DIM 64
#define I_DIM 64

__global__ __launch_bounds__(64) void conv_shift_kernel(
    const float* __restrict__ x, const float* __restrict__ w, float* __restrict__ y)
{
    const int o  = blockIdx.x;       // 0..55
    const int ig = blockIdx.y;       // 0..15 -> i in [ig*4, ig*4+4)
    const int n  = threadIdx.x;      // 0..63, active n < 56
    const int nc = (n < N_DIM) ? n : (N_DIM - 1);   // clamp for safe addressing

    const int rowA = (o + O_DIM - 1) % O_DIM;  // l=0 source row
    const int rowB = (o + O_DIM - 2) % O_DIM;  // l=1 source row

    float acc0 = 0.f, acc1 = 0.f, acc2 = 0.f, acc3 = 0.f;

    const int i0 = ig * 4;

    for (int j = 0; j < J_DIM; ++j) {
        const float* xa = x + (j * O_DIM + rowA) * N_DIM;
        const float* xb = x + (j * O_DIM + rowB) * N_DIM;

        const float aC = xa[nc];
        const float bC = xb[nc];
        const float aL = (nc > 0)         ? xa[nc - 1] : 0.f;
        const float aR = (nc < N_DIM - 1) ? xa[nc + 1] : 0.f;
        const float bL = (nc > 0)         ? xb[nc - 1] : 0.f;
        const float bR = (nc < N_DIM - 1) ? xb[nc + 1] : 0.f;

        // W[i,j,l,k] flat: (i*64 + j)*6 + l*3 + k ; block-uniform -> s_load
        const float* w0 = w + ((i0 + 0) * J_DIM + j) * 6;
        const float* w1 = w + ((i0 + 1) * J_DIM + j) * 6;
        const float* w2 = w + ((i0 + 2) * J_DIM + j) * 6;
        const float* w3 = w + ((i0 + 3) * J_DIM + j) * 6;

        acc0 += aL * w0[0] + aC * w0[1] + aR * w0[2]
              + bL * w0[3] + bC * w0[4] + bR * w0[5];
        acc1 += aL * w1[0] + aC * w1[1] + aR * w1[2]
              + bL * w1[3] + bC * w1[4] + bR * w1[5];
        acc2 += aL * w2[0] + aC * w2[1] + aR * w2[2]
              + bL * w2[3] + bC * w2[4] + bR * w2[5];
        acc3 += aL * w3[0] + aC * w3[1] + aR * w3[2]
              + bL * w3[3] + bC * w3[4] + bR * w3[5];
    }

    if (n < N_DIM) {
        y[((i0 + 0) * O_DIM + o) * N_DIM + n] = acc0;
        y[((i0 + 1) * O_DIM + o) * N_DIM + n] = acc1;
        y[((i0 + 2) * O_DIM + o) * N_DIM + n] = acc2;
        y[((i0 + 3) * O_DIM + o) * N_DIM + n] = acc3;
    }
}

extern "C" void kernel_launch(void* const* d_in, const int* in_sizes, int n_in,
                              void* d_out, int out_size, void* d_ws, size_t ws_size,
                              hipStream_t stream) {
    const float* x = (const float*)d_in[0];
    const float* w = (const float*)d_in[1];
    float* y = (float*)d_out;

    dim3 grid(O_DIM, I_DIM / 4);  // 56 x 16 = 896 single-wave blocks
    conv_shift_kernel<<<grid, 64, 0, stream>>>(x, w, y);
}